// Round 13
// baseline (128.844 us; speedup 1.0000x reference)
//
#include <hip/hip_runtime.h>

#define N_NODES 100000
#define D 64
#define N_EDGES 1200000
#define NCB 391              // coarse buckets of 256 dst nodes
#define NBLK 256             // partition blocks
#define PAD 16               // pad per-bucket total counters to 64B lines
#define CHUNK ((N_EDGES + NBLK - 1) / NBLK)   // 4688 edges per block

typedef __attribute__((ext_vector_type(8))) short short8v;           // 8 bf16 (MFMA frag)
typedef __attribute__((ext_vector_type(8))) unsigned short ushort8v; // 8 bf16 raw
typedef __attribute__((ext_vector_type(4))) float f32x4;

__device__ __forceinline__ unsigned short f2bf(float x) {
    unsigned int b = __float_as_uint(x);
    b += 0x7FFFu + ((b >> 16) & 1u);          // round-to-nearest-even
    return (unsigned short)(b >> 16);
}
__device__ __forceinline__ float bf2f(unsigned short u) {
    return __uint_as_float((unsigned int)u << 16);
}

// ---------- pass 1: per-block coarse histogram + bucket totals + fb + wb ----------
__global__ __launch_bounds__(256) void bin_hist(
    const int* __restrict__ eidx, int* __restrict__ hist, int* __restrict__ totP,
    const float* __restrict__ feat, ushort* __restrict__ fb,
    const float* __restrict__ W, ushort* __restrict__ wb)
{
    __shared__ int h[NCB];
    for (int i = threadIdx.x; i < NCB; i += 256) h[i] = 0;
    __syncthreads();
    const int blk = blockIdx.x;

    if (blk < 32) {
        int g  = blk * 256 + threadIdx.x;     // 0..8191
        int j  = g & 7;
        int l  = (g >> 3) & 63;
        int c4 = (g >> 9) & 3;
        int tt = g >> 11;
        int k   = 32 * tt + ((l >> 4) << 3) + j;
        int col = 16 * c4 + (l & 15);
        wb[g] = f2bf(W[k * 64 + col]);
    }

    const int beg = blk * CHUNK;
    const int end = min(beg + CHUNK, N_EDGES);
    for (int e = beg + threadIdx.x; e < end; e += 256)
        atomicAdd(&h[eidx[N_EDGES + e] >> 8], 1);

    const int total4 = N_NODES * D / 4;
    for (int i = blk * 256 + threadIdx.x; i < total4; i += NBLK * 256) {
        float4 v = ((const float4*)feat)[i];
        ushort4 o;
        o.x = f2bf(v.x); o.y = f2bf(v.y); o.z = f2bf(v.z); o.w = f2bf(v.w);
        ((ushort4*)fb)[i] = o;
    }

    __syncthreads();
    for (int i = threadIdx.x; i < NCB; i += 256) {
        int v = h[i];
        hist[blk * NCB + i] = v;
        if (v) atomicAdd(&totP[i * PAD], v);
    }
}

// ---------- pass 2: bucket bases + per-(block,bucket) run starts (parallel) ----------
__global__ __launch_bounds__(256) void rstart(
    const int* __restrict__ totP, const int* __restrict__ hist,
    int* __restrict__ boff, int* __restrict__ runstart, int* __restrict__ offs)
{
    __shared__ int red[256];
    __shared__ int pfx[256];
    __shared__ int bo_s;

    const int tid = threadIdx.x;
    const int i   = blockIdx.x;

    int p = 0;
    for (int j = tid; j < i; j += 256) p += totP[j * PAD];
    red[tid] = p;
    __syncthreads();
    for (int off = 128; off > 0; off >>= 1) {
        if (tid < off) red[tid] += red[tid + off];
        __syncthreads();
    }
    if (tid == 0) {
        bo_s = red[0];
        boff[i] = red[0];
        if (i == 0) { boff[NCB] = N_EDGES; offs[N_NODES] = N_EDGES; }
    }
    __syncthreads();

    int v = hist[tid * NCB + i];
    pfx[tid] = v;
    __syncthreads();
    for (int off = 1; off < 256; off <<= 1) {
        int x = (tid >= off) ? pfx[tid - off] : 0;
        __syncthreads();
        pfx[tid] += x;
        __syncthreads();
    }
    runstart[tid * NCB + i] = bo_s + pfx[tid] - v;
}

// ---------- pass 3: deterministic scatter into per-block sub-ranges ----------
__global__ __launch_bounds__(256) void bin_fill(
    const int* __restrict__ eidx, const int* __restrict__ runstart,
    unsigned int* __restrict__ pairs)
{
    __shared__ int lcur[NCB];
    const int blk = blockIdx.x;
    for (int i = threadIdx.x; i < NCB; i += 256) lcur[i] = runstart[blk * NCB + i];
    __syncthreads();
    const int beg = blk * CHUNK;
    const int end = min(beg + CHUNK, N_EDGES);
    for (int e = beg + threadIdx.x; e < end; e += 256) {
        int src = eidx[e];
        int dst = eidx[N_EDGES + e];
        int pos = atomicAdd(&lcur[dst >> 8], 1);
        pairs[pos] = ((unsigned int)src << 8) | (unsigned int)(dst & 255);
    }
}

// ---------- pass 4: fine sort within bucket -> offs[] + csr[] (packed) ----------
__global__ __launch_bounds__(256) void fine_sort(
    const unsigned int* __restrict__ pairs,
    const int* __restrict__ boff,
    int* __restrict__ offs,
    unsigned int* __restrict__ csr)
{
    __shared__ int cnt[256];
    __shared__ int pfx[256];
    __shared__ int lcur[256];

    const int tid = threadIdx.x;
    const int b   = blockIdx.x;
    const int beg = boff[b];
    const int end = boff[b + 1];

    cnt[tid] = 0;
    __syncthreads();
    for (int j = beg + tid; j < end; j += 256)
        atomicAdd(&cnt[pairs[j] & 255], 1);
    __syncthreads();

    int v = cnt[tid];
    pfx[tid] = v;
    __syncthreads();
    for (int off = 1; off < 256; off <<= 1) {
        int x = (tid >= off) ? pfx[tid - off] : 0;
        __syncthreads();
        pfx[tid] += x;
        __syncthreads();
    }
    int ex = pfx[tid] - v;
    lcur[tid] = ex;
    int gn = b * 256 + tid;
    if (gn < N_NODES) offs[gn] = beg + ex;
    __syncthreads();

    for (int j = beg + tid; j < end; j += 256) {
        unsigned int p = pairs[j];
        int pos = beg + atomicAdd(&lcur[p & 255], 1);
        csr[pos] = p;                 // keep packed (src<<8 | dst&255)
    }
}

// ---------- fused aggregate + MFMA linear: block = 32 nodes ----------
// Phase A: EDGE-BALANCED. Block edge range [offs[n0], offs[n0+32]) split into
// 32 equal chunks, one per octet (8 lanes, 16B each). Register accumulate,
// ds_add_f32 flush to f32 LDS accumulator on node change. Loads 4-deep.
// Phase B: deg from offs; mean frags from LDS f32; 4 waves x 2 MFMA tiles.
#define MSTR 68   // f32 accumulator row stride (272B, 16B-aligned)
__global__ __launch_bounds__(256) void agg_gemm(
    const ushort* __restrict__ fb,
    const int* __restrict__ offs,
    const unsigned int* __restrict__ csr,
    const ushort* __restrict__ wb,
    const float* __restrict__ bias,
    float* __restrict__ out)
{
    __shared__ __attribute__((aligned(16))) ushort wbl[8192];
    __shared__ __attribute__((aligned(16))) float macc[32 * MSTR];

    const int tid = threadIdx.x;
    const int n0  = blockIdx.x * 32;

    // wb -> LDS
    {
        const short8v* src = (const short8v*)wb;
        short8v* dst = (short8v*)wbl;
        #pragma unroll
        for (int r = 0; r < 4; ++r) dst[r * 256 + tid] = src[r * 256 + tid];
    }
    // zero the f32 accumulator
    #pragma unroll
    for (int i = 0; i < 9; ++i) {
        int idx = i * 256 + tid;
        if (idx < 32 * MSTR) macc[idx] = 0.0f;
    }
    __syncthreads();

    // ----- Phase A: edge-balanced gather -----
    const int l = tid & 7;                // lane within octet (dims 8l..8l+7)
    const int o = tid >> 3;               // octet 0..31
    const int base = offs[n0];
    const int L    = offs[n0 + 32] - base;
    const int ch   = (L + 31) >> 5;
    const int lim  = base + L;
    int j    = base + o * ch;
    int jend = j + ch; if (jend > lim) jend = lim;
    const ushort8v* f8 = (const ushort8v*)fb;
    const int nlow = n0 & 255;

    float s[8];
    #pragma unroll
    for (int k = 0; k < 8; ++k) s[k] = 0.0f;
    int cur = -1;

    #define ACC1(P, V)                                                        \
    {                                                                         \
        int nd = (int)((P) & 255u) - nlow;                                    \
        if (nd != cur) {                                                      \
            if (cur >= 0) {                                                   \
                float* mp = macc + cur * MSTR + l * 8;                        \
                _Pragma("unroll")                                             \
                for (int k = 0; k < 8; ++k) { atomicAdd(&mp[k], s[k]); s[k] = 0.0f; } \
            }                                                                 \
            cur = nd;                                                         \
        }                                                                     \
        _Pragma("unroll")                                                     \
        for (int k = 0; k < 8; ++k) s[k] += bf2f((V)[k]);                     \
    }

    for (; j + 4 <= jend; j += 4) {
        unsigned int p0 = csr[j], p1 = csr[j+1], p2 = csr[j+2], p3 = csr[j+3];
        ushort8v v0 = f8[(size_t)(p0 >> 8) * 8 + l];
        ushort8v v1 = f8[(size_t)(p1 >> 8) * 8 + l];
        ushort8v v2 = f8[(size_t)(p2 >> 8) * 8 + l];
        ushort8v v3 = f8[(size_t)(p3 >> 8) * 8 + l];
        ACC1(p0, v0) ACC1(p1, v1) ACC1(p2, v2) ACC1(p3, v3)
    }
    for (; j < jend; ++j) {
        unsigned int p = csr[j];
        ushort8v v = f8[(size_t)(p >> 8) * 8 + l];
        ACC1(p, v)
    }
    if (cur >= 0) {
        float* mp = macc + cur * MSTR + l * 8;
        #pragma unroll
        for (int k = 0; k < 8; ++k) atomicAdd(&mp[k], s[k]);
    }
    __syncthreads();

    // ----- Phase B: MFMA. wave wv: row-tile rt = wv>>1, col pair cp = wv&1 -----
    const int lane = tid & 63;
    const int wv   = tid >> 6;
    const int rt   = wv >> 1;
    const int cp   = wv & 1;
    const int kg   = lane >> 4;
    const int cl   = lane & 15;

    const int nn   = n0 + rt * 16 + cl;
    const int deg  = offs[nn + 1] - offs[nn];
    const float inv = 1.0f / (float)(deg > 1 ? deg : 1);

    const ushort* frow = fb + (size_t)nn * 64;
    short8v a0 = *(const short8v*)(frow + kg * 8);
    short8v a1 = *(const short8v*)(frow + 32 + kg * 8);

    const float* mrow = macc + (rt * 16 + cl) * MSTR;
    f32x4 q0 = *(const f32x4*)(mrow + kg * 8);
    f32x4 q1 = *(const f32x4*)(mrow + kg * 8 + 4);
    f32x4 q2 = *(const f32x4*)(mrow + 32 + kg * 8);
    f32x4 q3 = *(const f32x4*)(mrow + 32 + kg * 8 + 4);
    short8v a2, a3;
    #pragma unroll
    for (int k = 0; k < 4; ++k) {
        a2[k]     = (short)f2bf(q0[k] * inv);
        a2[k + 4] = (short)f2bf(q1[k] * inv);
        a3[k]     = (short)f2bf(q2[k] * inv);
        a3[k + 4] = (short)f2bf(q3[k] * inv);
    }

    #pragma unroll
    for (int q = 0; q < 2; ++q) {
        const int c4 = cp * 2 + q;
        float bv = bias[c4 * 16 + cl];
        f32x4 acc = (f32x4){bv, bv, bv, bv};
        acc = __builtin_amdgcn_mfma_f32_16x16x32_bf16(
            a0, *(const short8v*)(wbl + (size_t)((0 * 4 + c4) * 64 + lane) * 8), acc, 0, 0, 0);
        acc = __builtin_amdgcn_mfma_f32_16x16x32_bf16(
            a1, *(const short8v*)(wbl + (size_t)((1 * 4 + c4) * 64 + lane) * 8), acc, 0, 0, 0);
        acc = __builtin_amdgcn_mfma_f32_16x16x32_bf16(
            a2, *(const short8v*)(wbl + (size_t)((2 * 4 + c4) * 64 + lane) * 8), acc, 0, 0, 0);
        acc = __builtin_amdgcn_mfma_f32_16x16x32_bf16(
            a3, *(const short8v*)(wbl + (size_t)((3 * 4 + c4) * 64 + lane) * 8), acc, 0, 0, 0);
        #pragma unroll
        for (int r = 0; r < 4; ++r)
            out[(size_t)(n0 + rt * 16 + kg * 4 + r) * 64 + c4 * 16 + cl] = acc[r];
    }
}

extern "C" void kernel_launch(void* const* d_in, const int* in_sizes, int n_in,
                              void* d_out, int out_size, void* d_ws, size_t ws_size,
                              hipStream_t stream) {
    const float* feat = (const float*)d_in[0];
    const int*   eidx = (const int*)d_in[1];
    const float* W    = (const float*)d_in[2];
    const float* bias = (const float*)d_in[3];
    float* out = (float*)d_out;

    int* hist     = (int*)d_ws;                        // NBLK*NCB
    int* totP     = hist + NBLK * NCB;                 // NCB*PAD (memset)
    int* runstart = totP + NCB * PAD;                  // NBLK*NCB
    int* boff     = runstart + NBLK * NCB;             // NCB + 2
    int* offs     = boff + NCB + 2;                    // N_NODES + 1
    unsigned int* csr = (unsigned int*)(offs + N_NODES + 1);  // N_EDGES (packed)
    ushort* wb    = (ushort*)(csr + N_EDGES);          // 8192 bf16 W frag table
    unsigned int* pairs = (unsigned int*)(wb + 8192);  // N_EDGES
    ushort* fb    = (ushort*)(pairs + N_EDGES);        // N_NODES*D bf16

    hipMemsetAsync(totP, 0, (size_t)NCB * PAD * sizeof(int), stream);

    bin_hist<<<NBLK, 256, 0, stream>>>(eidx, hist, totP, feat, fb, W, wb);
    rstart<<<NCB, 256, 0, stream>>>(totP, hist, boff, runstart, offs);
    bin_fill<<<NBLK, 256, 0, stream>>>(eidx, runstart, pairs);
    fine_sort<<<NCB, 256, 0, stream>>>(pairs, boff, offs, csr);
    agg_gemm<<<N_NODES / 32, 256, 0, stream>>>(fb, offs, csr, wb, bias, out);
}